// Round 1
// baseline (1750.941 us; speedup 1.0000x reference)
//
#include <hip/hip_runtime.h>
#include <hip/hip_bf16.h>

#define N_NODESC 100000
#define N_EDGESC 1000000
#define N_QUERYC 100000

typedef short short8 __attribute__((ext_vector_type(8)));
typedef float f32x4 __attribute__((ext_vector_type(4)));

// ---------- dual-dtype load helper (flag: 1 = inputs are bf16, 0 = f32) ----------
__device__ __forceinline__ float ldf(const void* p, int i, int isbf) {
  return isbf ? __bfloat162float(((const __hip_bfloat16*)p)[i])
              : ((const float*)p)[i];
}
__device__ __forceinline__ unsigned short f2b(float x) {
  __hip_bfloat16 h = __float2bfloat16(x);
  return *(unsigned short*)&h;
}
__device__ __forceinline__ float b2f(unsigned int u) {
  return __uint_as_float(u << 16);
}
__device__ __forceinline__ void gload16(const void* g, void* l) {
  __builtin_amdgcn_global_load_lds(
      (const __attribute__((address_space(1))) void*)g,
      (__attribute__((address_space(3))) void*)l, 16, 0, 0);
}

// ---------- 0: sniff input dtype ----------
__global__ void k_sniff(const void* x, int* flag) {
  __shared__ int cnt;
  int t = threadIdx.x;
  if (t == 0) cnt = 0;
  __syncthreads();
  const unsigned short* h = (const unsigned short*)x;
  int local = 0;
  for (int i = t; i < 4096; i += 256) {
    int e = (h[i] >> 7) & 0xFF;
    if (e >= 107 && e <= 133) local++;
  }
  atomicAdd(&cnt, local);
  __syncthreads();
  if (t == 0) *flag = (cnt >= 3482) ? 1 : 0;
}

// ---------- 1: histogram of dst ----------
__global__ void k_hist(const int* __restrict__ dst, int* __restrict__ cnt, int ne) {
  int e = blockIdx.x * 256 + threadIdx.x;
  if (e < ne) atomicAdd(&cnt[dst[e]], 1);
}

// ---------- 2a: per-chunk exclusive scan ----------
__global__ void k_scan1(const int* __restrict__ cnt, int* __restrict__ off,
                        int* __restrict__ partials, int n) {
  __shared__ int s[1024];
  int t = threadIdx.x;
  int idx = blockIdx.x * 1024 + t;
  int v = (idx < n) ? cnt[idx] : 0;
  s[t] = v;
  __syncthreads();
  for (int d = 1; d < 1024; d <<= 1) {
    int tmp = (t >= d) ? s[t - d] : 0;
    __syncthreads();
    s[t] += tmp;
    __syncthreads();
  }
  if (idx < n) off[idx] = s[t] - v;
  if (t == 1023) partials[blockIdx.x] = s[1023];
}

// ---------- 2b: scan chunk totals ----------
__global__ void k_scan2(const int* __restrict__ partials, int* __restrict__ pref,
                        int* __restrict__ off, int nb, int npos) {
  __shared__ int s[128];
  int t = threadIdx.x;
  int v = (t < nb) ? partials[t] : 0;
  s[t] = v;
  __syncthreads();
  for (int d = 1; d < 128; d <<= 1) {
    int tmp = (t >= d) ? s[t - d] : 0;
    __syncthreads();
    s[t] += tmp;
    __syncthreads();
  }
  if (t < nb) pref[t] = s[t] - v;
  if (t == 127) off[npos] = s[127];
}

// ---------- 2c: apply chunk prefixes ----------
__global__ void k_scan3(int* __restrict__ off, const int* __restrict__ pref,
                        int* __restrict__ cursor, int n) {
  int i = blockIdx.x * 256 + threadIdx.x;
  if (i < n) {
    int o = off[i] + pref[i >> 10];
    off[i] = o;
    cursor[i] = o;
  }
}

// ---------- 3: bucket fill -> fused 16B edge record {src, m_lo, m_hi, 0} ----------
__global__ void k_fill(const int* __restrict__ ei,
                       const void* nr, const void* ni, const void* nj, const void* nk,
                       const int* __restrict__ flagp, int* __restrict__ cursor,
                       uint4* __restrict__ recs, int ne) {
  int isbf = *flagp;
  int e = blockIdx.x * 256 + threadIdx.x;
  if (e >= ne) return;
  int s = ei[e];
  int d = ei[ne + e];
  int pos = atomicAdd(&cursor[d], 1);
  uint4 r;
  r.x = (unsigned)s;
  r.y = (unsigned)f2b(-ldf(nr, e, isbf)) | ((unsigned)f2b(-ldf(ni, e, isbf)) << 16);
  r.z = (unsigned)f2b(-ldf(nj, e, isbf)) | ((unsigned)f2b(-ldf(nk, e, isbf)) << 16);
  r.w = 0;
  recs[pos] = r;
}

// ---------- 3b: interleave inputs -> Xg[node][feat][comp] bf16 ----------
__global__ __launch_bounds__(256) void k_ilv(
    const void* X0, const void* X1, const void* X2, const void* X3,
    const int* __restrict__ flagp, unsigned short* __restrict__ Xg, int n) {
  int isbf = *flagp;
  int lane = threadIdx.x & 63;
  int node = blockIdx.x * 4 + (threadIdx.x >> 6);
  if (node >= n) return;
  int idx = node * 64 + lane;
  unsigned int lo = f2b(ldf(X0, idx, isbf)) | ((unsigned int)f2b(ldf(X1, idx, isbf)) << 16);
  unsigned int hi = f2b(ldf(X2, idx, isbf)) | ((unsigned int)f2b(ldf(X3, idx, isbf)) << 16);
  uint2 g = make_uint2(lo, hi);
  *(uint2*)(Xg + (size_t)node * 256 + lane * 4) = g;
}

// ---------- 4: quaternion aggregation — persistent waves + sharded dynamic queue ----------
// One wave processes one node at a time; waves pull chunks of 2 nodes from one of
// 8 per-group atomic counters (group = blockIdx.x & 7, each owns a contiguous 1/8
// node range). This removes the workgroup-retirement imbalance (max-of-4 Poisson
// degree sums) that capped occupancy at 67%.
// Output: fragment-major Tf[(node>>4)*4096 + kc*512 + q*128 + (node&15)*8 + j]
#define AGG_CHUNK 2
__global__ __launch_bounds__(256, 8) void k_agg(
    const unsigned short* __restrict__ Xg, const int* __restrict__ off,
    const uint4* __restrict__ recs, unsigned short* __restrict__ Tf,
    int* __restrict__ qcnt, int nnodes) {
  __shared__ unsigned short tl[4][256];
  int lane = threadIdx.x & 63;
  int w = threadIdx.x >> 6;
  int grp = blockIdx.x & 7;
  int G = (nnodes + 7) >> 3;
  int gbase = grp * G;
  int gend = min(gbase + G, nnodes);

  for (;;) {
    int pos;
    if (lane == 0) pos = atomicAdd(&qcnt[grp], AGG_CHUNK);
    pos = __builtin_amdgcn_readfirstlane(pos);
    int n0 = gbase + pos;
    if (n0 >= gend) break;
    int n1 = min(n0 + AGG_CHUNK, gend);

    for (int node = n0; node < n1; ++node) {
      int rs = off[node], re = off[node + 1];
      float tr = 0.f, ti = 0.f, tj = 0.f, tk = 0.f;

      auto qacc = [&](uint2 g, unsigned mx, unsigned my) {
        float mr = __uint_as_float(mx << 16), mi = __uint_as_float(mx & 0xffff0000u);
        float mj = __uint_as_float(my << 16), mk = __uint_as_float(my & 0xffff0000u);
        float xr = __uint_as_float(g.x << 16), xi = __uint_as_float(g.x & 0xffff0000u);
        float xj = __uint_as_float(g.y << 16), xk = __uint_as_float(g.y & 0xffff0000u);
        tr += mr * xr - mi * xi - mj * xj - mk * xk;
        ti += mr * xi + mi * xr + mj * xk - mk * xj;
        tj += mr * xj - mi * xk + mj * xr + mk * xi;
        tk += mr * xk + mi * xj - mj * xi + mk * xr;
      };

      int e = rs;
      for (; e + 8 <= re; e += 8) {
        int ss[8];
        unsigned sx[8], sy[8];
#pragma unroll
        for (int u = 0; u < 8; u++) {
          uint4 r = recs[e + u];  // uniform address
          ss[u] = __builtin_amdgcn_readfirstlane((int)r.x);
          sx[u] = __builtin_amdgcn_readfirstlane(r.y);
          sy[u] = __builtin_amdgcn_readfirstlane(r.z);
        }
        uint2 g[8];
#pragma unroll
        for (int u = 0; u < 8; u++)
          g[u] = *(const uint2*)(Xg + (size_t)ss[u] * 256 + lane * 4);  // SGPR base + lane off
#pragma unroll
        for (int u = 0; u < 8; u++) qacc(g[u], sx[u], sy[u]);
      }
      for (; e < re; ++e) {
        uint4 r = recs[e];
        int s = __builtin_amdgcn_readfirstlane((int)r.x);
        unsigned mx = __builtin_amdgcn_readfirstlane(r.y);
        unsigned my = __builtin_amdgcn_readfirstlane(r.z);
        uint2 g0 = *(const uint2*)(Xg + (size_t)s * 256 + lane * 4);
        qacc(g0, mx, my);
      }

      // in-wave transpose: lane=f holds 4 comps -> 16B chunks in k-order
      tl[w][lane] = f2b(tr);
      tl[w][64 + lane] = f2b(ti);
      tl[w][128 + lane] = f2b(tj);
      tl[w][192 + lane] = f2b(tk);
      __builtin_amdgcn_wave_barrier();
      if (lane < 32) {
        uint4 v = *(const uint4*)&tl[w][lane * 8];
        size_t o = (size_t)(node >> 4) * 4096 + (lane >> 2) * 512 + (lane & 3) * 128 +
                   (node & 15) * 8;
        *(uint4*)(Tf + o) = v;
      }
      __builtin_amdgcn_wave_barrier();  // WAR fence before next node reuses tl[w]
    }
  }
}

// ---------- 5: build swizzled k-major base matrices Wq (4x64x64, 32KB) + bias ----------
// Wq[(w4*64 + h)*64 + ((kk>>3)^(h&7))*8 + (kk&7)] = W[w4][kk][h]  (bf16, NO sign)
__global__ void k_weff(const void* W, const void* b, const int* __restrict__ flagp,
                       unsigned short* __restrict__ Wq, float* __restrict__ bcat) {
  int isbf = *flagp;
  int t = blockIdx.x * 256 + threadIdx.x;  // 0..16383
  int w4 = t >> 12;
  int h = (t >> 6) & 63;
  int kk = t & 63;
  int s = (kk >> 3) ^ (h & 7);
  Wq[(w4 * 64 + h) * 64 + s * 8 + (kk & 7)] = f2b(ldf(W, w4 * 4096 + kk * 64 + h, isbf));
  if (t < 256) bcat[t] = ldf(b, t, isbf);
}

// ---------- 6: quaternion-structured MFMA GEMM, one barrier (unchanged R6) ----------
__global__ __launch_bounds__(256, 2) void k_gemm(
    const unsigned short* __restrict__ A, const unsigned short* __restrict__ Wq,
    const float* __restrict__ bias, int M, int mode,
    unsigned short* __restrict__ XgOut,
    float* __restrict__ P, const void* Cw, const int* __restrict__ flagp) {
  __shared__ unsigned short Wsm[16384];  // 32 KB

  int t = threadIdx.x;
  int lane = t & 63;
  int w = t >> 6;
  int l15 = lane & 15, quad = lane >> 4;
  int m0 = blockIdx.x * 64;
  int hh = (w & 1) * 32;

#pragma unroll
  for (int i = 0; i < 8; i++)
    gload16((const char*)Wq + (size_t)(i * 256 + t) * 16,
            (char*)Wsm + (size_t)(i * 256 + w * 64) * 16);
  __syncthreads();

  short8 av[2][8];
  int n16 = blockIdx.x * 4 + (w >> 1) * 2;
#pragma unroll
  for (int mi = 0; mi < 2; mi++)
#pragma unroll
    for (int kc = 0; kc < 8; kc++)
      av[mi][kc] = *(const short8*)(A + (size_t)(n16 + mi) * 4096 + kc * 512 + lane * 8);

  f32x4 acc[2][4][2];
#pragma unroll
  for (int mi = 0; mi < 2; mi++)
#pragma unroll
    for (int c = 0; c < 4; c++)
#pragma unroll
      for (int hb = 0; hb < 2; hb++) acc[mi][c][hb] = (f32x4){0.f, 0.f, 0.f, 0.f};

#pragma unroll
  for (int kc = 0; kc < 8; kc++) {
    int a = kc >> 1;
    short8 bv[4][2];
#pragma unroll
    for (int c = 0; c < 4; c++) {
      int w4 = a ^ c;
      int neg = (0x3950 >> (a * 4 + c)) & 1;
#pragma unroll
      for (int hb = 0; hb < 2; hb++) {
        int h = hh + hb * 16 + l15;
        int lc = ((kc & 1) * 4 + quad) ^ (l15 & 7);
        short8 bb = *(const short8*)&Wsm[(w4 * 64 + h) * 64 + lc * 8];
        if (neg) {
          uint4 u = *(uint4*)&bb;
          u.x ^= 0x80008000u; u.y ^= 0x80008000u;
          u.z ^= 0x80008000u; u.w ^= 0x80008000u;
          bb = *(short8*)&u;
        }
        bv[c][hb] = bb;
      }
    }
#pragma unroll
    for (int mi = 0; mi < 2; mi++)
#pragma unroll
      for (int c = 0; c < 4; c++)
#pragma unroll
        for (int hb = 0; hb < 2; hb++)
          acc[mi][c][hb] =
              __builtin_amdgcn_mfma_f32_16x16x32_bf16(av[mi][kc], bv[c][hb], acc[mi][c][hb], 0, 0, 0);
  }

  float bias_v[4][2];
#pragma unroll
  for (int c = 0; c < 4; c++)
#pragma unroll
    for (int hb = 0; hb < 2; hb++) bias_v[c][hb] = bias[c * 64 + hh + hb * 16 + l15];

  if (mode == 0) {
#pragma unroll
    for (int mi = 0; mi < 2; mi++) {
#pragma unroll
      for (int hb = 0; hb < 2; hb++) {
#pragma unroll
        for (int r = 0; r < 4; r++) {
          int node = m0 + (w >> 1) * 32 + mi * 16 + quad * 4 + r;
          unsigned int lo =
              f2b(fmaxf(acc[mi][0][hb][r] + bias_v[0][hb], 0.f)) |
              ((unsigned int)f2b(fmaxf(acc[mi][1][hb][r] + bias_v[1][hb], 0.f)) << 16);
          unsigned int hi =
              f2b(fmaxf(acc[mi][2][hb][r] + bias_v[2][hb], 0.f)) |
              ((unsigned int)f2b(fmaxf(acc[mi][3][hb][r] + bias_v[3][hb], 0.f)) << 16);
          *(uint2*)(XgOut + (size_t)node * 256 + (hh + hb * 16 + l15) * 4) =
              make_uint2(lo, hi);
        }
      }
    }
  } else {
    int isbf = *flagp;
    float cw[4][2][4];
#pragma unroll
    for (int c = 0; c < 4; c++)
#pragma unroll
      for (int hb = 0; hb < 2; hb++) {
        int h = hh + hb * 16 + l15;
#pragma unroll
        for (int d = 0; d < 2; d++)
#pragma unroll
          for (int e = 0; e < 2; e++)
            cw[c][hb][e + 2 * d] = ldf(Cw, d * 512 + c * 128 + e * 64 + h, isbf);
      }
#pragma unroll
    for (int mi = 0; mi < 2; mi++) {
#pragma unroll
      for (int r = 0; r < 4; r++) {
        int node = m0 + (w >> 1) * 32 + mi * 16 + quad * 4 + r;
        float pd0 = 0.f, pd1 = 0.f, pd2 = 0.f, pd3 = 0.f;
#pragma unroll
        for (int c = 0; c < 4; c++)
#pragma unroll
          for (int hb = 0; hb < 2; hb++) {
            float v = fmaxf(acc[mi][c][hb][r] + bias_v[c][hb], 0.f);
            pd0 += v * cw[c][hb][0];
            pd1 += v * cw[c][hb][1];
            pd2 += v * cw[c][hb][2];
            pd3 += v * cw[c][hb][3];
          }
#pragma unroll
        for (int o = 1; o < 16; o <<= 1) {
          pd0 += __shfl_xor(pd0, o);
          pd1 += __shfl_xor(pd1, o);
          pd2 += __shfl_xor(pd2, o);
          pd3 += __shfl_xor(pd3, o);
        }
        if (l15 == 0 && node < M) {
          atomicAdd(&P[node * 4 + 0], pd0);
          atomicAdd(&P[node * 4 + 1], pd1);
          atomicAdd(&P[node * 4 + 2], pd2);
          atomicAdd(&P[node * 4 + 3], pd3);
        }
      }
    }
  }
}

// ---------- 8: per-query logits + log_softmax ----------
__global__ void k_query(const int* __restrict__ qe, const float* __restrict__ P,
                        const void* Cb, const int* __restrict__ flagp,
                        void* out, int nq) {
  int isbf = *flagp;
  int q = blockIdx.x * 256 + threadIdx.x;
  if (q >= nq) return;
  int q0 = qe[q * 2], q1 = qe[q * 2 + 1];
  float l0 = P[q0 * 4 + 0] + P[q1 * 4 + 1] + ldf(Cb, 0, isbf);
  float l1 = P[q0 * 4 + 2] + P[q1 * 4 + 3] + ldf(Cb, 1, isbf);
  float m = fmaxf(l0, l1);
  float lse = m + logf(expf(l0 - m) + expf(l1 - m));
  float o0 = l0 - lse, o1 = l1 - lse;
  if (isbf) {
    __hip_bfloat16* o = (__hip_bfloat16*)out;
    o[q * 2] = __float2bfloat16(o0);
    o[q * 2 + 1] = __float2bfloat16(o1);
  } else {
    float* o = (float*)out;
    o[q * 2] = o0;
    o[q * 2 + 1] = o1;
  }
}

extern "C" void kernel_launch(void* const* d_in, const int* in_sizes, int n_in,
                              void* d_out, int out_size, void* d_ws, size_t ws_size,
                              hipStream_t stream) {
  const int N = N_NODESC, NE = N_EDGESC, NQ = N_QUERYC;
  const int NPAD = 100224;  // >= 1563*64 = 100032

  char* w = (char*)d_ws;
  auto alloc = [&](size_t bytes) -> void* {
    void* p = (void*)w;
    w += (bytes + 255) & ~(size_t)255;
    return p;
  };
  int* flag       = (int*)alloc(4);
  int* offsets    = (int*)alloc((size_t)(N + 1) * 4);
  int* cursor     = (int*)alloc((size_t)N * 4);
  int* partials   = (int*)alloc(128 * 4);
  int* pref       = (int*)alloc(128 * 4);
  int* qcnt       = (int*)alloc(16 * 4);   // 8 queue counters per k_agg launch
  uint4* recs     = (uint4*)alloc((size_t)NE * 16);
  unsigned short* Tf = (unsigned short*)alloc((size_t)NPAD * 256 * 2);
  unsigned short* Xg = (unsigned short*)alloc((size_t)NPAD * 256 * 2);
  unsigned short* Wq = (unsigned short*)alloc(16384 * 2);
  float* bcat     = (float*)alloc(256 * 4);
  float* P        = (float*)alloc((size_t)N * 4 * 4);
  (void)ws_size; (void)n_in; (void)in_sizes; (void)out_size;

  const int* ei = (const int*)d_in[8];

  k_sniff<<<1, 256, 0, stream>>>(d_in[0], flag);

  // CSR build
  hipMemsetAsync(cursor, 0, (size_t)N * 4, stream);
  hipMemsetAsync(P, 0, (size_t)N * 16, stream);
  hipMemsetAsync(qcnt, 0, 16 * 4, stream);
  k_hist<<<(NE + 255) / 256, 256, 0, stream>>>(ei + NE, cursor, NE);
  k_scan1<<<(N + 1023) / 1024, 1024, 0, stream>>>(cursor, offsets, partials, N);
  k_scan2<<<1, 128, 0, stream>>>(partials, pref, offsets, (N + 1023) / 1024, N);
  k_scan3<<<(N + 255) / 256, 256, 0, stream>>>(offsets, pref, cursor, N);
  k_fill<<<(NE + 255) / 256, 256, 0, stream>>>(ei, d_in[4], d_in[5], d_in[6], d_in[7],
                                               flag, cursor, recs, NE);

  // layer-1 gather source
  k_ilv<<<(N + 3) / 4, 256, 0, stream>>>(d_in[0], d_in[1], d_in[2], d_in[3], flag, Xg, N);

  int ggrid = (N + 63) / 64;

  // layer 1
  k_agg<<<2048, 256, 0, stream>>>(Xg, offsets, recs, Tf, qcnt, N);
  k_weff<<<64, 256, 0, stream>>>(d_in[10], d_in[11], flag, Wq, bcat);
  k_gemm<<<ggrid, 256, 0, stream>>>(Tf, Wq, bcat, N, 0, Xg, nullptr, nullptr, flag);

  // layer 2 (+fused readout partial dots)
  k_agg<<<2048, 256, 0, stream>>>(Xg, offsets, recs, Tf, qcnt + 8, N);
  k_weff<<<64, 256, 0, stream>>>(d_in[12], d_in[13], flag, Wq, bcat);
  k_gemm<<<ggrid, 256, 0, stream>>>(Tf, Wq, bcat, N, 1, nullptr, P, d_in[14], flag);

  // queries
  k_query<<<(NQ + 255) / 256, 256, 0, stream>>>((const int*)d_in[9], P, d_in[15],
                                                flag, d_out, NQ);
}

// Round 2
// 553.462 us; speedup vs baseline: 3.1636x; 3.1636x over previous
//
#include <hip/hip_runtime.h>
#include <hip/hip_bf16.h>

#define N_NODESC 100000
#define N_EDGESC 1000000
#define N_QUERYC 100000

typedef short short8 __attribute__((ext_vector_type(8)));
typedef short s16x2 __attribute__((ext_vector_type(2)));
typedef float f32x4 __attribute__((ext_vector_type(4)));

// ---------- dual-dtype load helper (flag: 1 = inputs are bf16, 0 = f32) ----------
__device__ __forceinline__ float ldf(const void* p, int i, int isbf) {
  return isbf ? __bfloat162float(((const __hip_bfloat16*)p)[i])
              : ((const float*)p)[i];
}
__device__ __forceinline__ unsigned short f2b(float x) {
  __hip_bfloat16 h = __float2bfloat16(x);
  return *(unsigned short*)&h;
}
__device__ __forceinline__ float b2f(unsigned int u) {
  return __uint_as_float(u << 16);
}
__device__ __forceinline__ s16x2 u2s(unsigned u) {
  union { unsigned u; s16x2 s; } c; c.u = u; return c.s;
}
__device__ __forceinline__ void gload16(const void* g, void* l) {
  __builtin_amdgcn_global_load_lds(
      (const __attribute__((address_space(1))) void*)g,
      (__attribute__((address_space(3))) void*)l, 16, 0, 0);
}

// ---------- 0: sniff input dtype ----------
__global__ void k_sniff(const void* x, int* flag) {
  __shared__ int cnt;
  int t = threadIdx.x;
  if (t == 0) cnt = 0;
  __syncthreads();
  const unsigned short* h = (const unsigned short*)x;
  int local = 0;
  for (int i = t; i < 4096; i += 256) {
    int e = (h[i] >> 7) & 0xFF;
    if (e >= 107 && e <= 133) local++;
  }
  atomicAdd(&cnt, local);
  __syncthreads();
  if (t == 0) *flag = (cnt >= 3482) ? 1 : 0;
}

// ---------- 1: histogram of dst ----------
__global__ void k_hist(const int* __restrict__ dst, int* __restrict__ cnt, int ne) {
  int e = blockIdx.x * 256 + threadIdx.x;
  if (e < ne) atomicAdd(&cnt[dst[e]], 1);
}

// ---------- 2a: per-chunk exclusive scan ----------
__global__ void k_scan1(const int* __restrict__ cnt, int* __restrict__ off,
                        int* __restrict__ partials, int n) {
  __shared__ int s[1024];
  int t = threadIdx.x;
  int idx = blockIdx.x * 1024 + t;
  int v = (idx < n) ? cnt[idx] : 0;
  s[t] = v;
  __syncthreads();
  for (int d = 1; d < 1024; d <<= 1) {
    int tmp = (t >= d) ? s[t - d] : 0;
    __syncthreads();
    s[t] += tmp;
    __syncthreads();
  }
  if (idx < n) off[idx] = s[t] - v;
  if (t == 1023) partials[blockIdx.x] = s[1023];
}

// ---------- 2b: scan chunk totals ----------
__global__ void k_scan2(const int* __restrict__ partials, int* __restrict__ pref,
                        int* __restrict__ off, int nb, int npos) {
  __shared__ int s[128];
  int t = threadIdx.x;
  int v = (t < nb) ? partials[t] : 0;
  s[t] = v;
  __syncthreads();
  for (int d = 1; d < 128; d <<= 1) {
    int tmp = (t >= d) ? s[t - d] : 0;
    __syncthreads();
    s[t] += tmp;
    __syncthreads();
  }
  if (t < nb) pref[t] = s[t] - v;
  if (t == 127) off[npos] = s[127];
}

// ---------- 2c: apply chunk prefixes ----------
__global__ void k_scan3(int* __restrict__ off, const int* __restrict__ pref,
                        int* __restrict__ cursor, int n) {
  int i = blockIdx.x * 256 + threadIdx.x;
  if (i < n) {
    int o = off[i] + pref[i >> 10];
    off[i] = o;
    cursor[i] = o;
  }
}

// ---------- 3: bucket fill -> fused 16B edge record {src, m_lo, m_hi, 0} ----------
__global__ void k_fill(const int* __restrict__ ei,
                       const void* nr, const void* ni, const void* nj, const void* nk,
                       const int* __restrict__ flagp, int* __restrict__ cursor,
                       uint4* __restrict__ recs, int ne) {
  int isbf = *flagp;
  int e = blockIdx.x * 256 + threadIdx.x;
  if (e >= ne) return;
  int s = ei[e];
  int d = ei[ne + e];
  int pos = atomicAdd(&cursor[d], 1);
  uint4 r;
  r.x = (unsigned)s;
  r.y = (unsigned)f2b(-ldf(nr, e, isbf)) | ((unsigned)f2b(-ldf(ni, e, isbf)) << 16);
  r.z = (unsigned)f2b(-ldf(nj, e, isbf)) | ((unsigned)f2b(-ldf(nk, e, isbf)) << 16);
  r.w = 0;
  recs[pos] = r;
}

// ---------- 3b: interleave inputs -> Xg[node][feat][comp] bf16 ----------
__global__ __launch_bounds__(256) void k_ilv(
    const void* X0, const void* X1, const void* X2, const void* X3,
    const int* __restrict__ flagp, unsigned short* __restrict__ Xg, int n) {
  int isbf = *flagp;
  int lane = threadIdx.x & 63;
  int node = blockIdx.x * 4 + (threadIdx.x >> 6);
  if (node >= n) return;
  int idx = node * 64 + lane;
  unsigned int lo = f2b(ldf(X0, idx, isbf)) | ((unsigned int)f2b(ldf(X1, idx, isbf)) << 16);
  unsigned int hi = f2b(ldf(X2, idx, isbf)) | ((unsigned int)f2b(ldf(X3, idx, isbf)) << 16);
  uint2 g = make_uint2(lo, hi);
  *(uint2*)(Xg + (size_t)node * 256 + lane * 4) = g;
}

// ---------- 4: quaternion aggregation (wave/node, scalar metadata, R0 structure) ----------
// R1 post-mortem: dynamic atomic queues serialize at the device coherence point
// (~100+ ns per same-line RMW) -> 8x regression. Static mapping restored.
// R2: quaternion accumulate via v_dot2_f32_bf16 — data is already pair-packed
// (g.x=(xr,xi), g.y=(xj,xk); m-pairs wave-uniform in SGPRs, sign/swap variants
// built in SALU for free). 8 dot2 per edge replaces ~26 VALU ops.
// Output: fragment-major Tf[(node>>4)*4096 + kc*512 + q*128 + (node&15)*8 + j]
#if __has_builtin(__builtin_amdgcn_fdot2_f32_bf16)
#define USE_DOT2 1
#else
#define USE_DOT2 0
#endif
__global__ __launch_bounds__(256, 8) void k_agg(
    const unsigned short* __restrict__ Xg, const int* __restrict__ off,
    const uint4* __restrict__ recs, unsigned short* __restrict__ Tf, int nnodes) {
  __shared__ unsigned short tl[4][256];
  int lane = threadIdx.x & 63;
  int w = threadIdx.x >> 6;
  int node = __builtin_amdgcn_readfirstlane(blockIdx.x * 4 + w);
  if (node >= nnodes) return;
  int rs = off[node], re = off[node + 1];
  float tr = 0.f, ti = 0.f, tj = 0.f, tk = 0.f;

  auto qacc = [&](uint2 g, unsigned mx, unsigned my) {
#if USE_DOT2
    // a=(mr,mi) b=(mj,mk) packed bf16x2, wave-uniform -> variants in SALU
    unsigned a = mx, b = my;
    unsigned sa = (a >> 16) | (a << 16);        // (mi, mr)
    unsigned sb = (b >> 16) | (b << 16);        // (mk, mj)
    unsigned A1 = a ^ 0x80000000u;              // (mr, -mi)
    unsigned A2 = b ^ 0x80008000u;              // (-mj, -mk)
    unsigned B2 = sb ^ 0x00008000u;             // (-mk, mj)
    unsigned D2 = sb ^ 0x80000000u;             // (mk, -mj)
    s16x2 gx = u2s(g.x), gy = u2s(g.y);         // (xr,xi), (xj,xk)
    tr = __builtin_amdgcn_fdot2_f32_bf16(u2s(A1), gx, tr, false);  // mr*xr - mi*xi
    tr = __builtin_amdgcn_fdot2_f32_bf16(u2s(A2), gy, tr, false);  // -mj*xj - mk*xk
    ti = __builtin_amdgcn_fdot2_f32_bf16(u2s(sa), gx, ti, false);  // mi*xr + mr*xi
    ti = __builtin_amdgcn_fdot2_f32_bf16(u2s(B2), gy, ti, false);  // -mk*xj + mj*xk
    tj = __builtin_amdgcn_fdot2_f32_bf16(u2s(b),  gx, tj, false);  // mj*xr + mk*xi
    tj = __builtin_amdgcn_fdot2_f32_bf16(u2s(A1), gy, tj, false);  // mr*xj - mi*xk
    tk = __builtin_amdgcn_fdot2_f32_bf16(u2s(D2), gx, tk, false);  // mk*xr - mj*xi
    tk = __builtin_amdgcn_fdot2_f32_bf16(u2s(sa), gy, tk, false);  // mi*xj + mr*xk
#else
    float mr = __uint_as_float(mx << 16), mi = __uint_as_float(mx & 0xffff0000u);
    float mj = __uint_as_float(my << 16), mk = __uint_as_float(my & 0xffff0000u);
    float xr = __uint_as_float(g.x << 16), xi = __uint_as_float(g.x & 0xffff0000u);
    float xj = __uint_as_float(g.y << 16), xk = __uint_as_float(g.y & 0xffff0000u);
    tr += mr * xr - mi * xi - mj * xj - mk * xk;
    ti += mr * xi + mi * xr + mj * xk - mk * xj;
    tj += mr * xj - mi * xk + mj * xr + mk * xi;
    tk += mr * xk + mi * xj - mj * xi + mk * xr;
#endif
  };

  int e = rs;
  for (; e + 8 <= re; e += 8) {
    int ss[8];
    unsigned sx[8], sy[8];
#pragma unroll
    for (int u = 0; u < 8; u++) {
      uint4 r = recs[e + u];  // uniform address
      ss[u] = __builtin_amdgcn_readfirstlane((int)r.x);
      sx[u] = __builtin_amdgcn_readfirstlane(r.y);
      sy[u] = __builtin_amdgcn_readfirstlane(r.z);
    }
    uint2 g[8];
#pragma unroll
    for (int u = 0; u < 8; u++)
      g[u] = *(const uint2*)(Xg + (size_t)ss[u] * 256 + lane * 4);  // SGPR base + lane off
#pragma unroll
    for (int u = 0; u < 8; u++) qacc(g[u], sx[u], sy[u]);
  }
  for (; e < re; ++e) {
    uint4 r = recs[e];
    int s = __builtin_amdgcn_readfirstlane((int)r.x);
    unsigned mx = __builtin_amdgcn_readfirstlane(r.y);
    unsigned my = __builtin_amdgcn_readfirstlane(r.z);
    uint2 g0 = *(const uint2*)(Xg + (size_t)s * 256 + lane * 4);
    qacc(g0, mx, my);
  }

  // in-wave transpose: lane=f holds 4 comps -> 16B chunks in k-order
  tl[w][lane] = f2b(tr);
  tl[w][64 + lane] = f2b(ti);
  tl[w][128 + lane] = f2b(tj);
  tl[w][192 + lane] = f2b(tk);
  __builtin_amdgcn_wave_barrier();
  if (lane < 32) {
    uint4 v = *(const uint4*)&tl[w][lane * 8];
    size_t o = (size_t)(node >> 4) * 4096 + (lane >> 2) * 512 + (lane & 3) * 128 +
               (node & 15) * 8;
    *(uint4*)(Tf + o) = v;
  }
}

// ---------- 5: build swizzled k-major base matrices Wq (4x64x64, 32KB) + bias ----------
// Wq[(w4*64 + h)*64 + ((kk>>3)^(h&7))*8 + (kk&7)] = W[w4][kk][h]  (bf16, NO sign)
__global__ void k_weff(const void* W, const void* b, const int* __restrict__ flagp,
                       unsigned short* __restrict__ Wq, float* __restrict__ bcat) {
  int isbf = *flagp;
  int t = blockIdx.x * 256 + threadIdx.x;  // 0..16383
  int w4 = t >> 12;
  int h = (t >> 6) & 63;
  int kk = t & 63;
  int s = (kk >> 3) ^ (h & 7);
  Wq[(w4 * 64 + h) * 64 + s * 8 + (kk & 7)] = f2b(ldf(W, w4 * 4096 + kk * 64 + h, isbf));
  if (t < 256) bcat[t] = ldf(b, t, isbf);
}

// ---------- 6: quaternion-structured MFMA GEMM, one barrier (unchanged R6) ----------
__global__ __launch_bounds__(256, 2) void k_gemm(
    const unsigned short* __restrict__ A, const unsigned short* __restrict__ Wq,
    const float* __restrict__ bias, int M, int mode,
    unsigned short* __restrict__ XgOut,
    float* __restrict__ P, const void* Cw, const int* __restrict__ flagp) {
  __shared__ unsigned short Wsm[16384];  // 32 KB

  int t = threadIdx.x;
  int lane = t & 63;
  int w = t >> 6;
  int l15 = lane & 15, quad = lane >> 4;
  int m0 = blockIdx.x * 64;
  int hh = (w & 1) * 32;

#pragma unroll
  for (int i = 0; i < 8; i++)
    gload16((const char*)Wq + (size_t)(i * 256 + t) * 16,
            (char*)Wsm + (size_t)(i * 256 + w * 64) * 16);
  __syncthreads();

  short8 av[2][8];
  int n16 = blockIdx.x * 4 + (w >> 1) * 2;
#pragma unroll
  for (int mi = 0; mi < 2; mi++)
#pragma unroll
    for (int kc = 0; kc < 8; kc++)
      av[mi][kc] = *(const short8*)(A + (size_t)(n16 + mi) * 4096 + kc * 512 + lane * 8);

  f32x4 acc[2][4][2];
#pragma unroll
  for (int mi = 0; mi < 2; mi++)
#pragma unroll
    for (int c = 0; c < 4; c++)
#pragma unroll
      for (int hb = 0; hb < 2; hb++) acc[mi][c][hb] = (f32x4){0.f, 0.f, 0.f, 0.f};

#pragma unroll
  for (int kc = 0; kc < 8; kc++) {
    int a = kc >> 1;
    short8 bv[4][2];
#pragma unroll
    for (int c = 0; c < 4; c++) {
      int w4 = a ^ c;
      int neg = (0x3950 >> (a * 4 + c)) & 1;
#pragma unroll
      for (int hb = 0; hb < 2; hb++) {
        int h = hh + hb * 16 + l15;
        int lc = ((kc & 1) * 4 + quad) ^ (l15 & 7);
        short8 bb = *(const short8*)&Wsm[(w4 * 64 + h) * 64 + lc * 8];
        if (neg) {
          uint4 u = *(uint4*)&bb;
          u.x ^= 0x80008000u; u.y ^= 0x80008000u;
          u.z ^= 0x80008000u; u.w ^= 0x80008000u;
          bb = *(short8*)&u;
        }
        bv[c][hb] = bb;
      }
    }
#pragma unroll
    for (int mi = 0; mi < 2; mi++)
#pragma unroll
      for (int c = 0; c < 4; c++)
#pragma unroll
        for (int hb = 0; hb < 2; hb++)
          acc[mi][c][hb] =
              __builtin_amdgcn_mfma_f32_16x16x32_bf16(av[mi][kc], bv[c][hb], acc[mi][c][hb], 0, 0, 0);
  }

  float bias_v[4][2];
#pragma unroll
  for (int c = 0; c < 4; c++)
#pragma unroll
    for (int hb = 0; hb < 2; hb++) bias_v[c][hb] = bias[c * 64 + hh + hb * 16 + l15];

  if (mode == 0) {
#pragma unroll
    for (int mi = 0; mi < 2; mi++) {
#pragma unroll
      for (int hb = 0; hb < 2; hb++) {
#pragma unroll
        for (int r = 0; r < 4; r++) {
          int node = m0 + (w >> 1) * 32 + mi * 16 + quad * 4 + r;
          unsigned int lo =
              f2b(fmaxf(acc[mi][0][hb][r] + bias_v[0][hb], 0.f)) |
              ((unsigned int)f2b(fmaxf(acc[mi][1][hb][r] + bias_v[1][hb], 0.f)) << 16);
          unsigned int hi =
              f2b(fmaxf(acc[mi][2][hb][r] + bias_v[2][hb], 0.f)) |
              ((unsigned int)f2b(fmaxf(acc[mi][3][hb][r] + bias_v[3][hb], 0.f)) << 16);
          *(uint2*)(XgOut + (size_t)node * 256 + (hh + hb * 16 + l15) * 4) =
              make_uint2(lo, hi);
        }
      }
    }
  } else {
    int isbf = *flagp;
    float cw[4][2][4];
#pragma unroll
    for (int c = 0; c < 4; c++)
#pragma unroll
      for (int hb = 0; hb < 2; hb++) {
        int h = hh + hb * 16 + l15;
#pragma unroll
        for (int d = 0; d < 2; d++)
#pragma unroll
          for (int e = 0; e < 2; e++)
            cw[c][hb][e + 2 * d] = ldf(Cw, d * 512 + c * 128 + e * 64 + h, isbf);
      }
#pragma unroll
    for (int mi = 0; mi < 2; mi++) {
#pragma unroll
      for (int r = 0; r < 4; r++) {
        int node = m0 + (w >> 1) * 32 + mi * 16 + quad * 4 + r;
        float pd0 = 0.f, pd1 = 0.f, pd2 = 0.f, pd3 = 0.f;
#pragma unroll
        for (int c = 0; c < 4; c++)
#pragma unroll
          for (int hb = 0; hb < 2; hb++) {
            float v = fmaxf(acc[mi][c][hb][r] + bias_v[c][hb], 0.f);
            pd0 += v * cw[c][hb][0];
            pd1 += v * cw[c][hb][1];
            pd2 += v * cw[c][hb][2];
            pd3 += v * cw[c][hb][3];
          }
#pragma unroll
        for (int o = 1; o < 16; o <<= 1) {
          pd0 += __shfl_xor(pd0, o);
          pd1 += __shfl_xor(pd1, o);
          pd2 += __shfl_xor(pd2, o);
          pd3 += __shfl_xor(pd3, o);
        }
        if (l15 == 0 && node < M) {
          atomicAdd(&P[node * 4 + 0], pd0);
          atomicAdd(&P[node * 4 + 1], pd1);
          atomicAdd(&P[node * 4 + 2], pd2);
          atomicAdd(&P[node * 4 + 3], pd3);
        }
      }
    }
  }
}

// ---------- 8: per-query logits + log_softmax ----------
__global__ void k_query(const int* __restrict__ qe, const float* __restrict__ P,
                        const void* Cb, const int* __restrict__ flagp,
                        void* out, int nq) {
  int isbf = *flagp;
  int q = blockIdx.x * 256 + threadIdx.x;
  if (q >= nq) return;
  int q0 = qe[q * 2], q1 = qe[q * 2 + 1];
  float l0 = P[q0 * 4 + 0] + P[q1 * 4 + 1] + ldf(Cb, 0, isbf);
  float l1 = P[q0 * 4 + 2] + P[q1 * 4 + 3] + ldf(Cb, 1, isbf);
  float m = fmaxf(l0, l1);
  float lse = m + logf(expf(l0 - m) + expf(l1 - m));
  float o0 = l0 - lse, o1 = l1 - lse;
  if (isbf) {
    __hip_bfloat16* o = (__hip_bfloat16*)out;
    o[q * 2] = __float2bfloat16(o0);
    o[q * 2 + 1] = __float2bfloat16(o1);
  } else {
    float* o = (float*)out;
    o[q * 2] = o0;
    o[q * 2 + 1] = o1;
  }
}

extern "C" void kernel_launch(void* const* d_in, const int* in_sizes, int n_in,
                              void* d_out, int out_size, void* d_ws, size_t ws_size,
                              hipStream_t stream) {
  const int N = N_NODESC, NE = N_EDGESC, NQ = N_QUERYC;
  const int NPAD = 100224;  // >= 1563*64 = 100032

  char* w = (char*)d_ws;
  auto alloc = [&](size_t bytes) -> void* {
    void* p = (void*)w;
    w += (bytes + 255) & ~(size_t)255;
    return p;
  };
  int* flag       = (int*)alloc(4);
  int* offsets    = (int*)alloc((size_t)(N + 1) * 4);
  int* cursor     = (int*)alloc((size_t)N * 4);
  int* partials   = (int*)alloc(128 * 4);
  int* pref       = (int*)alloc(128 * 4);
  uint4* recs     = (uint4*)alloc((size_t)NE * 16);
  unsigned short* Tf = (unsigned short*)alloc((size_t)NPAD * 256 * 2);
  unsigned short* Xg = (unsigned short*)alloc((size_t)NPAD * 256 * 2);
  unsigned short* Wq = (unsigned short*)alloc(16384 * 2);
  float* bcat     = (float*)alloc(256 * 4);
  float* P        = (float*)alloc((size_t)N * 4 * 4);
  (void)ws_size; (void)n_in; (void)in_sizes; (void)out_size;

  const int* ei = (const int*)d_in[8];

  k_sniff<<<1, 256, 0, stream>>>(d_in[0], flag);

  // CSR build
  hipMemsetAsync(cursor, 0, (size_t)N * 4, stream);
  hipMemsetAsync(P, 0, (size_t)N * 16, stream);
  k_hist<<<(NE + 255) / 256, 256, 0, stream>>>(ei + NE, cursor, NE);
  k_scan1<<<(N + 1023) / 1024, 1024, 0, stream>>>(cursor, offsets, partials, N);
  k_scan2<<<1, 128, 0, stream>>>(partials, pref, offsets, (N + 1023) / 1024, N);
  k_scan3<<<(N + 255) / 256, 256, 0, stream>>>(offsets, pref, cursor, N);
  k_fill<<<(NE + 255) / 256, 256, 0, stream>>>(ei, d_in[4], d_in[5], d_in[6], d_in[7],
                                               flag, cursor, recs, NE);

  // layer-1 gather source
  k_ilv<<<(N + 3) / 4, 256, 0, stream>>>(d_in[0], d_in[1], d_in[2], d_in[3], flag, Xg, N);

  int ggrid = (N + 63) / 64;

  // layer 1
  k_agg<<<(N + 3) / 4, 256, 0, stream>>>(Xg, offsets, recs, Tf, N);
  k_weff<<<64, 256, 0, stream>>>(d_in[10], d_in[11], flag, Wq, bcat);
  k_gemm<<<ggrid, 256, 0, stream>>>(Tf, Wq, bcat, N, 0, Xg, nullptr, nullptr, flag);

  // layer 2 (+fused readout partial dots)
  k_agg<<<(N + 3) / 4, 256, 0, stream>>>(Xg, offsets, recs, Tf, N);
  k_weff<<<64, 256, 0, stream>>>(d_in[12], d_in[13], flag, Wq, bcat);
  k_gemm<<<ggrid, 256, 0, stream>>>(Tf, Wq, bcat, N, 1, nullptr, P, d_in[14], flag);

  // queries
  k_query<<<(NQ + 255) / 256, 256, 0, stream>>>((const int*)d_in[9], P, d_in[15],
                                                flag, d_out, NQ);
}